// Round 10
// baseline (980.851 us; speedup 1.0000x reference)
//
#include <hip/hip_runtime.h>

#define TT 2048
#define BB 256
#define XX 64
#define HH 128
#define YY 32
#define HSTR 36    // h slice stride: 32 data + 4 pad floats (banks disjoint)
#define CSTR 132   // c ring row: 128 data + 4 pad floats

// Producer/consumer wave specialization. 1024 threads = 16 waves = 4/SIMD.
// Waves 0-7 (consumers): h-recurrence, J=1 output per quad, Kg=4 (kq=lane&3,
//   h-slice h[32kq..+32)); butterfly = xor1+xor2 quad_perm ONLY (both exact).
// Waves 8-15 (producers): c_t = SC*(W_ih x_t + b_ih + b_hh) TWO steps ahead
//   into a 4-slot LDS ring; reg-only + prefetched x => never stall on h; their
//   issue fills the consumers' post-barrier ds_read-h stall (R9: 450 idle
//   cyc/step from symmetric waves stalling in lockstep).
// Ring slot s written at step s-2, read at step s: 2 barriers apart. 1
// barrier/step. R3: bias after reduction (rides in c). R5: quad_perm only.
// R6: waves_per_eu exact pin. R7: pk_fma half-rate (saves decode only).

typedef float v2f __attribute__((ext_vector_type(2)));
typedef float v4f __attribute__((ext_vector_type(4)));

#define PKFMA(acc, a, b)                                              \
    asm("v_pk_fma_f32 %0, %1, %2, %0 op_sel:[0,0,0] op_sel_hi:[1,1,1]"\
        : "+v"(acc) : "v"(a), "v"(b))

template<int CTRL>
static __device__ __forceinline__ float dpp_add(float s) {
    return s + __int_as_float(__builtin_amdgcn_update_dpp(
        0, __float_as_int(s), CTRL, 0xF, 0xF, true));
}

static __device__ __forceinline__ void pin2(v2f& v) {
    asm volatile("" : "+v"(v));
}

#define LO2(v) __builtin_shufflevector(v, v, 0, 1)
#define HI2(v) __builtin_shufflevector(v, v, 2, 3)

__global__ __launch_bounds__(1024)
__attribute__((amdgpu_waves_per_eu(4, 4)))
void rnn_persist_kernel(const float* __restrict__ x,
                        const float* __restrict__ W_ih,
                        const float* __restrict__ W_hh,
                        const float* __restrict__ b_ih,
                        const float* __restrict__ b_hh,
                        const float* __restrict__ W_out,
                        const float* __restrict__ b_out,
                        float* __restrict__ out)
{
    __shared__ __align__(16) float h_lds[2][4 * HSTR];
    __shared__ __align__(16) float c_lds[4][CSTR];

    const int tid  = threadIdx.x;
    const int b    = blockIdx.x;
    const int w    = tid >> 6;          // 0..15
    const int lane = tid & 63;
    const int kq   = lane & 3;          // k-group within quad
    const int q    = lane >> 2;         // 0..15
    const bool cons = (w < 8);
    const int jq   = (cons ? w : (w - 8)) * 16 + q;   // 0..127

    const float SC = 2.8853900817779268f;  // 2*log2(e)

    v2f whh[16];     // consumer: W_hh[jq][32kq..+32), prescaled
    v2f wih[8];      // producer: W_ih[jq][16kq..+16), prescaled
    float cb = 0.f;  // producer: prescaled bias

    if (cons) {
        const v2f* ph = (const v2f*)(W_hh + jq * HH + kq * 32);
        #pragma unroll
        for (int c = 0; c < 16; ++c) { whh[c] = ph[c] * SC; pin2(whh[c]); }
    } else {
        const v2f* pi = (const v2f*)(W_ih + jq * XX + kq * 16);
        #pragma unroll
        for (int c = 0; c < 8; ++c) { wih[c] = pi[c] * SC; pin2(wih[c]); }
        cb = (b_ih[jq] + b_hh[jq]) * SC;
    }

    const float* xg = x + (size_t)b * TT * XX + kq * 16;
    const int hw_off = (jq >> 5) * HSTR + (jq & 31);  // h write slot

    if (tid < 4 * HSTR) h_lds[0][tid] = 0.f;

#define PRODSTEP(XR, SLOT)                                                 \
    do {                                                                   \
        const v2f* xx = (const v2f*)(XR);                                  \
        v2f pa = {0.f,0.f}, pc = {0.f,0.f};                                \
        PKFMA(pa, wih[0], xx[0]); PKFMA(pc, wih[1], xx[1]);                \
        PKFMA(pa, wih[2], xx[2]); PKFMA(pc, wih[3], xx[3]);                \
        PKFMA(pa, wih[4], xx[4]); PKFMA(pc, wih[5], xx[5]);                \
        PKFMA(pa, wih[6], xx[6]); PKFMA(pc, wih[7], xx[7]);                \
        pa = pa + pc;                                                      \
        float u = pa.x + pa.y;                                             \
        u = dpp_add<0xB1>(u);   /* quad_perm [1,0,3,2] = xor1 (exact) */   \
        u = dpp_add<0x4E>(u);   /* quad_perm [2,3,0,1] = xor2 (exact) */   \
        u += cb;                /* bias AFTER reduction (R3) */            \
        if (kq == 0) c_lds[SLOT][jq] = u;                                  \
    } while (0)

#define CONSSTEP(RP, WP, SLOT)                                             \
    do {                                                                   \
        const v4f* hp = (const v4f*)&h_lds[RP][kq * HSTR];                 \
        const v4f H0=hp[0], H1=hp[1], H2=hp[2], H3=hp[3];                  \
        const v4f H4=hp[4], H5=hp[5], H6=hp[6], H7=hp[7];                  \
        const float cval = c_lds[SLOT][jq];                                \
        v2f ca={0.f,0.f}, cbk={0.f,0.f}, cc={0.f,0.f}, cd={0.f,0.f};       \
        PKFMA(ca, whh[0],  LO2(H0)); PKFMA(cbk, whh[1],  HI2(H0));         \
        PKFMA(cc, whh[2],  LO2(H1)); PKFMA(cd,  whh[3],  HI2(H1));         \
        PKFMA(ca, whh[4],  LO2(H2)); PKFMA(cbk, whh[5],  HI2(H2));         \
        PKFMA(cc, whh[6],  LO2(H3)); PKFMA(cd,  whh[7],  HI2(H3));         \
        PKFMA(ca, whh[8],  LO2(H4)); PKFMA(cbk, whh[9],  HI2(H4));         \
        PKFMA(cc, whh[10], LO2(H5)); PKFMA(cd,  whh[11], HI2(H5));         \
        PKFMA(ca, whh[12], LO2(H6)); PKFMA(cbk, whh[13], HI2(H6));         \
        PKFMA(cc, whh[14], LO2(H7)); PKFMA(cd,  whh[15], HI2(H7));         \
        const v2f s2 = (ca + cbk) + (cc + cd);                             \
        float u = s2.x + s2.y;                                             \
        u = dpp_add<0xB1>(u);   /* xor1 */                                 \
        u = dpp_add<0x4E>(u);   /* xor2 */                                 \
        u += cval;              /* c = SC*(W_ih x + bias), reduced */      \
        const float e  = __builtin_amdgcn_exp2f(u);                        \
        const float hn = fmaf(-2.f, __builtin_amdgcn_rcpf(e + 1.f), 1.f); \
        if (kq == 0) h_lds[WP][hw_off] = hn;                               \
    } while (0)

    v4f xA[4], xB[4];

    // ---- prologue: producers fill ring slots 0,1; prefetch x(2),x(3) ----
    if (!cons) {
        #pragma unroll
        for (int i = 0; i < 4; ++i) xA[i] = ((const v4f*)xg)[i];          // x(0)
        PRODSTEP(xA, 0);
        #pragma unroll
        for (int i = 0; i < 4; ++i) xA[i] = ((const v4f*)(xg + XX))[i];   // x(1)
        PRODSTEP(xA, 1);
        #pragma unroll
        for (int i = 0; i < 4; ++i) xA[i] = ((const v4f*)(xg + 2 * XX))[i];
        #pragma unroll
        for (int i = 0; i < 4; ++i) xB[i] = ((const v4f*)(xg + 3 * XX))[i];
    }
    __syncthreads();

    for (int t = 0; t < TT; t += 2) {
        // even step: read h buf0 -> write buf1, consume c slot t&3
        if (cons) {
            CONSSTEP(0, 1, (t & 3));
        } else {
            PRODSTEP(xA, ((t + 2) & 3));
            const int tn = (t + 4 < TT) ? t + 4 : TT - 1;
            const v4f* xp = (const v4f*)(xg + (size_t)tn * XX);
            #pragma unroll
            for (int i = 0; i < 4; ++i) xA[i] = xp[i];
        }
        __syncthreads();
        // odd step: read buf1 -> write buf0, consume c slot (t+1)&3
        if (cons) {
            CONSSTEP(1, 0, ((t + 1) & 3));
        } else {
            PRODSTEP(xB, ((t + 3) & 3));
            const int tn = (t + 5 < TT) ? t + 5 : TT - 1;
            const v4f* xp = (const v4f*)(xg + (size_t)tn * XX);
            #pragma unroll
            for (int i = 0; i < 4; ++i) xB[i] = xp[i];
        }
        __syncthreads();
    }
#undef PRODSTEP
#undef CONSSTEP

    // ---- readout: out[b, :] = h_last @ W_out^T + b_out (h in buffer 0) ----
    if (tid < YY) {
        const float* h  = h_lds[0];
        const float* wr = W_out + tid * HH;
        float r0 = 0.f, r1 = 0.f, r2 = 0.f, r3 = 0.f;
        #pragma unroll
        for (int s = 0; s < 4; ++s) {     // 4 slices of 32 floats
            #pragma unroll
            for (int c = 0; c < 8; ++c) {
                const float4 wv = *(const float4*)(wr + s * 32 + c * 4);
                const float4 hv = *(const float4*)(h + s * HSTR + c * 4);
                r0 = fmaf(wv.x, hv.x, r0); r1 = fmaf(wv.y, hv.y, r1);
                r2 = fmaf(wv.z, hv.z, r2); r3 = fmaf(wv.w, hv.w, r3);
            }
        }
        out[b * YY + tid] = b_out[tid] + ((r0 + r1) + (r2 + r3));
    }
}

extern "C" void kernel_launch(void* const* d_in, const int* in_sizes, int n_in,
                              void* d_out, int out_size, void* d_ws, size_t ws_size,
                              hipStream_t stream) {
    const float* x     = (const float*)d_in[0];
    const float* W_ih  = (const float*)d_in[1];
    const float* W_hh  = (const float*)d_in[2];
    const float* b_ih  = (const float*)d_in[3];
    const float* b_hh  = (const float*)d_in[4];
    const float* W_out = (const float*)d_in[5];
    const float* b_out = (const float*)d_in[6];
    float* out = (float*)d_out;

    rnn_persist_kernel<<<BB, 1024, 0, stream>>>(x, W_ih, W_hh, b_ih, b_hh,
                                                W_out, b_out, out);
}

// Round 11
// 760.065 us; speedup vs baseline: 1.2905x; 1.2905x over previous
//
#include <hip/hip_runtime.h>

#define TT 2048
#define BB 256
#define XX 64
#define HH 128
#define YY 32

// Systolic h-distribution. 512 threads = 8 waves = 2 waves/SIMD.
// lane bits: l2={0,1} chunk/output-offset, jh={2}, mk={3,4,5} (8 k-groups).
// Thread outputs jA = w*16+jh*8+l2, jB = jA+4; k-range h[16mk..+16).
// Each lane reads ONE b128 (chunk l2 of its k-range); quad_perm [1,2,3,0]
// (ctrl 0x39, full explicit permutation - no direction ambiguity) circulates
// chunks; weights loaded lane-permuted (chunk (l2+r)&3) so rounds are
// compile-time.  DS insts/CU/step: 32 -> 8 reads (R9 was DS-heavy + one
// LDS-latency-exposed path per step).
// Reduction over mk: merge J=2 on bit3 (cndmask + row_ror:8 = xor8,
// direction-agnostic), xor16 = ds_swizzle 0x401F (documented pattern),
// xor32 = v_permlane32_swap pair-add (VALU).  All preserve l2,jh.
// R3: bias after reduction | R5: only direction-proof exchanges | R6/R10:
// uniform wave roles + waves_per_eu exact, else allocator spills weights.

typedef float v2f __attribute__((ext_vector_type(2)));
typedef float v4f __attribute__((ext_vector_type(4)));

#define PKFMA(acc, a, b)                                              \
    asm("v_pk_fma_f32 %0, %1, %2, %0 op_sel:[0,0,0] op_sel_hi:[1,1,1]"\
        : "+v"(acc) : "v"(a), "v"(b))

template<int CTRL>
static __device__ __forceinline__ float dpp_mov(float s) {
    return __int_as_float(__builtin_amdgcn_update_dpp(
        0, __float_as_int(s), CTRL, 0xF, 0xF, true));
}

// rotate quad: lane i receives lane (i+1)&3's value (quad_perm [1,2,3,0])
static __device__ __forceinline__ v4f rot_quad(v4f h) {
    v4f r;
    r.x = dpp_mov<0x39>(h.x);
    r.y = dpp_mov<0x39>(h.y);
    r.z = dpp_mov<0x39>(h.z);
    r.w = dpp_mov<0x39>(h.w);
    return r;
}

static __device__ __forceinline__ void pin2(v2f& v) {
    asm volatile("" : "+v"(v));
}

#define LO2(v) __builtin_shufflevector(v, v, 0, 1)
#define HI2(v) __builtin_shufflevector(v, v, 2, 3)

__global__ __launch_bounds__(512)
__attribute__((amdgpu_waves_per_eu(2, 2)))
void rnn_persist_kernel(const float* __restrict__ x,
                        const float* __restrict__ W_ih,
                        const float* __restrict__ W_hh,
                        const float* __restrict__ b_ih,
                        const float* __restrict__ b_hh,
                        const float* __restrict__ W_out,
                        const float* __restrict__ b_out,
                        float* __restrict__ out)
{
    __shared__ __align__(16) float h_lds[2][HH];

    const int tid  = threadIdx.x;
    const int b    = blockIdx.x;
    const int w    = tid >> 6;           // 0..7
    const int lane = tid & 63;
    const int l2   = lane & 3;           // chunk / output-offset
    const int jh   = (lane >> 2) & 1;
    const int mk   = lane >> 3;          // 0..7 k-group
    const int o    = mk & 1;             // merge-scatter select (lane bit3)
    const int jA   = w * 16 + jh * 8 + l2;
    const int jB   = jA + 4;

    const float SC = 2.8853900817779268f;  // 2*log2(e)

    // ---- weights, lane-permuted by rotation schedule, prescaled, pinned ----
    // round r uses h-chunk (l2+r)&3; wa[2r],wa[2r+1] = that chunk's W row part
    v2f wa[8], wb[8];    // W_hh[jA / jB][16mk + 4*((l2+r)&3) .. +4)
    v2f wia[4], wib[4];  // W_ih[jA / jB][8mk .. +8)
    #pragma unroll
    for (int r = 0; r < 4; ++r) {
        const int ch = (l2 + r) & 3;
        const v2f* pa = (const v2f*)(W_hh + jA * HH + 16 * mk + 4 * ch);
        const v2f* pb = (const v2f*)(W_hh + jB * HH + 16 * mk + 4 * ch);
        wa[2*r] = pa[0] * SC; wa[2*r+1] = pa[1] * SC;
        wb[2*r] = pb[0] * SC; wb[2*r+1] = pb[1] * SC;
    }
    {
        const v2f* pia = (const v2f*)(W_ih + jA * XX + 8 * mk);
        const v2f* pib = (const v2f*)(W_ih + jB * XX + 8 * mk);
        #pragma unroll
        for (int c = 0; c < 4; ++c) { wia[c] = pia[c] * SC; wib[c] = pib[c] * SC; }
    }
    #pragma unroll
    for (int c = 0; c < 8; ++c) { pin2(wa[c]); pin2(wb[c]); }
    #pragma unroll
    for (int c = 0; c < 4; ++c) { pin2(wia[c]); pin2(wib[c]); }

    const float bsel = (o ? (b_ih[jB] + b_hh[jB]) : (b_ih[jA] + b_hh[jA])) * SC;
    const int   jwr  = w * 16 + jh * 8 + o * 4 + l2;   // writer's output slot

    const float* xg = x + (size_t)b * TT * XX + 8 * mk;

    if (tid < HH) h_lds[0][tid] = 0.f;

    v4f xa0 = ((const v4f*)xg)[0];
    v4f xa1 = ((const v4f*)xg)[1];
    v4f xb0 = ((const v4f*)(xg + XX))[0];
    v4f xb1 = ((const v4f*)(xg + XX))[1];
    __syncthreads();

#define STEP(RP, WP, X0, X1)                                               \
    do {                                                                   \
        v4f hc = *(const v4f*)&h_lds[RP][16 * mk + 4 * l2];                \
        v2f aA = {0.f,0.f}, aA2 = {0.f,0.f};                               \
        v2f aB = {0.f,0.f}, aB2 = {0.f,0.f};                               \
        /* x-part first: independent of h, fills ds_read latency */        \
        PKFMA(aA, wia[0], LO2(X0)); PKFMA(aA2, wia[1], HI2(X0));           \
        PKFMA(aA, wia[2], LO2(X1)); PKFMA(aA2, wia[3], HI2(X1));           \
        PKFMA(aB, wib[0], LO2(X0)); PKFMA(aB2, wib[1], HI2(X0));           \
        PKFMA(aB, wib[2], LO2(X1)); PKFMA(aB2, wib[3], HI2(X1));           \
        /* 4 systolic rounds */                                            \
        PKFMA(aA, wa[0], LO2(hc)); PKFMA(aA2, wa[1], HI2(hc));             \
        PKFMA(aB, wb[0], LO2(hc)); PKFMA(aB2, wb[1], HI2(hc));             \
        hc = rot_quad(hc);                                                 \
        PKFMA(aA, wa[2], LO2(hc)); PKFMA(aA2, wa[3], HI2(hc));             \
        PKFMA(aB, wb[2], LO2(hc)); PKFMA(aB2, wb[3], HI2(hc));             \
        hc = rot_quad(hc);                                                 \
        PKFMA(aA, wa[4], LO2(hc)); PKFMA(aA2, wa[5], HI2(hc));             \
        PKFMA(aB, wb[4], LO2(hc)); PKFMA(aB2, wb[5], HI2(hc));             \
        hc = rot_quad(hc);                                                 \
        PKFMA(aA, wa[6], LO2(hc)); PKFMA(aA2, wa[7], HI2(hc));             \
        PKFMA(aB, wb[6], LO2(hc)); PKFMA(aB2, wb[7], HI2(hc));             \
        aA = aA + aA2; aB = aB + aB2;                                      \
        const float sA = aA.x + aA.y;                                      \
        const float sB = aB.x + aB.y;                                      \
        /* reduce over mk bits {3,4,5}, merging J=2 outputs on bit3 */     \
        float u  = o ? sB : sA;                                            \
        float vv = o ? sA : sB;                                            \
        u += dpp_mov<0x128>(vv);            /* row_ror:8 = xor8 */         \
        u += __int_as_float(__builtin_amdgcn_ds_swizzle(                   \
                 __float_as_int(u), 0x401F));  /* xor16 */                 \
        {                                                                  \
            float pa_ = u, pb_ = u;                                        \
            asm("v_permlane32_swap_b32 %0, %1" : "+v"(pa_), "+v"(pb_));    \
            u = pa_ + pb_;                  /* xor32 */                    \
        }                                                                  \
        u += bsel;                          /* bias AFTER reduction */     \
        const float e  = __builtin_amdgcn_exp2f(u);                        \
        const float hn = fmaf(-2.f, __builtin_amdgcn_rcpf(e + 1.f), 1.f); \
        if (lane < 16) h_lds[WP][jwr] = hn;                                \
        __syncthreads();                                                   \
    } while (0)

    for (int t = 0; t < TT; t += 2) {
        STEP(0, 1, xa0, xa1);
        {   // prefetch x for t+2
            const int tn = (t + 2 < TT) ? t + 2 : TT - 1;
            const v4f* xp = (const v4f*)(xg + (size_t)tn * XX);
            xa0 = xp[0]; xa1 = xp[1];
        }
        STEP(1, 0, xb0, xb1);
        {   // prefetch x for t+3
            const int tn = (t + 3 < TT) ? t + 3 : TT - 1;
            const v4f* xp = (const v4f*)(xg + (size_t)tn * XX);
            xb0 = xp[0]; xb1 = xp[1];
        }
    }
#undef STEP

    // ---- readout: out[b, :] = h_last @ W_out^T + b_out (h in buffer 0) ----
    if (tid < YY) {
        const float* h  = h_lds[0];
        const float* wr = W_out + tid * HH;
        float r0 = 0.f, r1 = 0.f, r2 = 0.f, r3 = 0.f;
        #pragma unroll
        for (int c = 0; c < 32; ++c) {
            const float4 wv = *(const float4*)(wr + c * 4);
            const float4 hv = *(const float4*)(h + c * 4);
            r0 = fmaf(wv.x, hv.x, r0); r1 = fmaf(wv.y, hv.y, r1);
            r2 = fmaf(wv.z, hv.z, r2); r3 = fmaf(wv.w, hv.w, r3);
        }
        out[b * YY + tid] = b_out[tid] + ((r0 + r1) + (r2 + r3));
    }
}

extern "C" void kernel_launch(void* const* d_in, const int* in_sizes, int n_in,
                              void* d_out, int out_size, void* d_ws, size_t ws_size,
                              hipStream_t stream) {
    const float* x     = (const float*)d_in[0];
    const float* W_ih  = (const float*)d_in[1];
    const float* W_hh  = (const float*)d_in[2];
    const float* b_ih  = (const float*)d_in[3];
    const float* b_hh  = (const float*)d_in[4];
    const float* W_out = (const float*)d_in[5];
    const float* b_out = (const float*)d_in[6];
    float* out = (float*)d_out;

    rnn_persist_kernel<<<BB, 512, 0, stream>>>(x, W_ih, W_hh, b_ih, b_hh,
                                               W_out, b_out, out);
}

// Round 12
// 722.937 us; speedup vs baseline: 1.3568x; 1.0514x over previous
//
#include <hip/hip_runtime.h>

#define TT 2048
#define BB 256
#define XX 64
#define HH 128
#define YY 32
#define SSTR 12           // 8 data + 4 pad floats per kg-slice
#define HBUF (16 * SSTR)  // 192 floats per h buffer

// 1024 threads = 16 waves = 4 waves/SIMD (R8's util=73%) with R9's lean
// reduce-scatter (1 tanh/thread) + pipelined x-partials (corridor fill).
// lane bits: kg = lane&15 (bits 0-3; h[8kg..+8), x[4kg..+4)),
//            jgl = lane>>4 (bits 4,5); jg = w*4+jgl; j = 2jg + b3.
// Butterfly (R11 lesson: keep it VALU-only, short path):
//   xor1,xor2 on BOTH s0,s1 (quad_perm, exact) -> quads uniform in bits 0,1;
//   merge J=2 on bit3 via row_ror:8 (direction-agnostic);
//   xor4 via row_half_mirror (flips bits 0,1,2: 0,1 uniform, bit3 preserved).
//   half_mirror is ONLY legal pre-merge-bit -- order matters.
// x-partials for step t+1 computed AFTER step t's h-write (fills the
// tail->barrier->ds_read corridor that left R9 at 46% util).
// R3: bias after reduction | R5: direction-proof exchanges only | R6:
// waves_per_eu exact pin | R7: pk_fma half-rate | R11: no DS ops in path.

typedef float v2f __attribute__((ext_vector_type(2)));
typedef float v4f __attribute__((ext_vector_type(4)));

#define PKFMA(acc, a, b)                                              \
    asm("v_pk_fma_f32 %0, %1, %2, %0 op_sel:[0,0,0] op_sel_hi:[1,1,1]"\
        : "+v"(acc) : "v"(a), "v"(b))

template<int CTRL>
static __device__ __forceinline__ float dpp_mov(float s) {
    return __int_as_float(__builtin_amdgcn_update_dpp(
        0, __float_as_int(s), CTRL, 0xF, 0xF, true));
}

static __device__ __forceinline__ void pin2(v2f& v) {
    asm volatile("" : "+v"(v));
}

#define LO2(v) __builtin_shufflevector(v, v, 0, 1)
#define HI2(v) __builtin_shufflevector(v, v, 2, 3)

__global__ __launch_bounds__(1024)
__attribute__((amdgpu_waves_per_eu(4, 4)))
void rnn_persist_kernel(const float* __restrict__ x,
                        const float* __restrict__ W_ih,
                        const float* __restrict__ W_hh,
                        const float* __restrict__ b_ih,
                        const float* __restrict__ b_hh,
                        const float* __restrict__ W_out,
                        const float* __restrict__ b_out,
                        float* __restrict__ out)
{
    __shared__ __align__(16) float h_lds[2][HBUF];

    const int tid  = threadIdx.x;
    const int b    = blockIdx.x;
    const int w    = tid >> 6;            // 0..15
    const int lane = tid & 63;
    const int kg   = lane & 15;           // k-group, lane bits {0,1,2,3}
    const int jgl  = lane >> 4;           // 0..3
    const int jg   = w * 4 + jgl;         // 0..63
    const int j0   = jg * 2;
    const int b3   = (lane >> 3) & 1;     // output select (merge bit)

    const float SC = 2.8853900817779268f;  // 2*log2(e)

    // ---- weights (24 floats, prescaled), pinned ----
    v2f whh2[2][4];   // per jj: 8 floats of W_hh k-slice
    v2f wih2[2][2];   // per jj: 4 floats of W_ih k-slice
    float bs[2];
    #pragma unroll
    for (int jj = 0; jj < 2; ++jj) {
        const v2f* ph = (const v2f*)(W_hh + (j0 + jj) * HH + kg * 8);
        #pragma unroll
        for (int c = 0; c < 4; ++c) whh2[jj][c] = ph[c] * SC;
        const v2f* pi = (const v2f*)(W_ih + (j0 + jj) * XX + kg * 4);
        #pragma unroll
        for (int c = 0; c < 2; ++c) wih2[jj][c] = pi[c] * SC;
        bs[jj] = (b_ih[j0 + jj] + b_hh[j0 + jj]) * SC;
    }
    #pragma unroll
    for (int jj = 0; jj < 2; ++jj) {
        #pragma unroll
        for (int c = 0; c < 4; ++c) pin2(whh2[jj][c]);
        pin2(wih2[jj][0]); pin2(wih2[jj][1]);
    }
    const float bsel = b3 ? bs[1] : bs[0];
    const int   jw   = j0 + b3;                      // writer's output
    const int   woff = (jw >> 3) * SSTR + (jw & 7);  // its LDS slot
    const bool  writer = (lane & 7) == 0;

    const float* xg = x + (size_t)b * TT * XX + kg * 4;

    if (tid < HBUF) h_lds[0][tid] = 0.f;

    // prologue: x-partials for step 0; xa=x(1), xb=x(2)
    v2f sxA0 = {0.f, 0.f}, sxA1 = {0.f, 0.f};
    v2f sxB0, sxB1;
    {
        const v4f x0 = *(const v4f*)xg;
        PKFMA(sxA0, wih2[0][0], LO2(x0)); PKFMA(sxA0, wih2[0][1], HI2(x0));
        PKFMA(sxA1, wih2[1][0], LO2(x0)); PKFMA(sxA1, wih2[1][1], HI2(x0));
    }
    v4f xa = *(const v4f*)(xg + XX);
    v4f xb = *(const v4f*)(xg + 2 * XX);
    __syncthreads();

#define STEP(RP, WP, SXU0, SXU1, SXF0, SXF1, XSRC, PRE, XPF)               \
    do {                                                                   \
        const v4f* hp = (const v4f*)&h_lds[RP][kg * SSTR];                 \
        const v4f H0 = hp[0], H1 = hp[1];                                  \
        v2f a0 = SXU0, a1 = SXU1;                                          \
        PKFMA(a0, whh2[0][0], LO2(H0)); PKFMA(a0, whh2[0][1], HI2(H0));    \
        PKFMA(a0, whh2[0][2], LO2(H1)); PKFMA(a0, whh2[0][3], HI2(H1));    \
        PKFMA(a1, whh2[1][0], LO2(H0)); PKFMA(a1, whh2[1][1], HI2(H0));    \
        PKFMA(a1, whh2[1][2], LO2(H1)); PKFMA(a1, whh2[1][3], HI2(H1));    \
        float s0 = a0.x + a0.y;                                            \
        float s1 = a1.x + a1.y;                                            \
        s0 += dpp_mov<0xB1>(s0);  s1 += dpp_mov<0xB1>(s1);  /* xor1 */     \
        s0 += dpp_mov<0x4E>(s0);  s1 += dpp_mov<0x4E>(s1);  /* xor2 */     \
        float u  = b3 ? s1 : s0;                                           \
        float vv = b3 ? s0 : s1;                                           \
        u += dpp_mov<0x128>(vv);   /* merge on bit3: row_ror:8 = xor8 */   \
        u += dpp_mov<0x141>(u);    /* xor4: half_mirror (pre-merge bits     \
                                      0,1 uniform; bit3 preserved) */      \
        u += bsel;                 /* bias AFTER reduction (R3) */         \
        const float e  = __builtin_amdgcn_exp2f(u);                        \
        const float hn = fmaf(-2.f, __builtin_amdgcn_rcpf(e + 1.f), 1.f); \
        if (writer) h_lds[WP][woff] = hn;                                  \
        /* corridor fill: x-partials for NEXT step + prefetch */           \
        SXF0 = (v2f){0.f, 0.f}; SXF1 = (v2f){0.f, 0.f};                    \
        PKFMA(SXF0, wih2[0][0], LO2(XSRC)); PKFMA(SXF0, wih2[0][1], HI2(XSRC)); \
        PKFMA(SXF1, wih2[1][0], LO2(XSRC)); PKFMA(SXF1, wih2[1][1], HI2(XSRC)); \
        { const int tn_ = (PRE) < TT ? (PRE) : TT - 1;                     \
          XPF = *(const v4f*)(xg + (size_t)tn_ * XX); }                    \
        __syncthreads();                                                   \
    } while (0)

    for (int t = 0; t < TT; t += 2) {
        // even: read buf0 -> write buf1; consume sxA; fill sxB from xa=x(t+1)
        STEP(0, 1, sxA0, sxA1, sxB0, sxB1, xa, t + 3, xa);
        // odd: read buf1 -> write buf0; consume sxB; fill sxA from xb=x(t+2)
        STEP(1, 0, sxB0, sxB1, sxA0, sxA1, xb, t + 4, xb);
    }
#undef STEP

    // ---- readout: out[b, :] = h_last @ W_out^T + b_out (h in buffer 0) ----
    if (tid < YY) {
        const float* h  = h_lds[0];
        const float* wr = W_out + tid * HH;
        float r0 = 0.f, r1 = 0.f, r2 = 0.f, r3 = 0.f;
        #pragma unroll
        for (int s16 = 0; s16 < 16; ++s16) {   // 16 slices of 8 floats
            #pragma unroll
            for (int c = 0; c < 2; ++c) {
                const float4 wv = *(const float4*)(wr + s16 * 8 + c * 4);
                const float4 hv = *(const float4*)(h + s16 * SSTR + c * 4);
                r0 = fmaf(wv.x, hv.x, r0); r1 = fmaf(wv.y, hv.y, r1);
                r2 = fmaf(wv.z, hv.z, r2); r3 = fmaf(wv.w, hv.w, r3);
            }
        }
        out[b * YY + tid] = b_out[tid] + ((r0 + r1) + (r2 + r3));
    }
}

extern "C" void kernel_launch(void* const* d_in, const int* in_sizes, int n_in,
                              void* d_out, int out_size, void* d_ws, size_t ws_size,
                              hipStream_t stream) {
    const float* x     = (const float*)d_in[0];
    const float* W_ih  = (const float*)d_in[1];
    const float* W_hh  = (const float*)d_in[2];
    const float* b_ih  = (const float*)d_in[3];
    const float* b_hh  = (const float*)d_in[4];
    const float* W_out = (const float*)d_in[5];
    const float* b_out = (const float*)d_in[6];
    float* out = (float*)d_out;

    rnn_persist_kernel<<<BB, 1024, 0, stream>>>(x, W_ih, W_hh, b_ih, b_hh,
                                                W_out, b_out, out);
}

// Round 13
// 588.758 us; speedup vs baseline: 1.6660x; 1.2279x over previous
//
#include <hip/hip_runtime.h>

#define TT 2048
#define BB 256
#define XX 64
#define HH 128
#define YY 32
#define SSTR 20          // 16 data + 4 pad floats per kg-slice
#define HBUF (8 * SSTR)  // 160 floats per h buffer

// R9 (champion, 590us) + two isolated changes:
//  1) step-loop barrier = s_waitcnt lgkmcnt(0) + raw s_barrier (m139/m201
//     pattern). __syncthreads() drains vmcnt(0) every step, exposing the
//     x-prefetch's HBM latency (~250-300 cyc/step, the unexplained idle).
//     LDS h-exchange only needs lgkmcnt; x loads ride across the barrier.
//  2) weights+bias prescaled by 2*log2(e) -> exp2(u) direct (no on-chain mul).
// Structure: 512 thr = 8 waves = 2/SIMD. J=2, Kg=8; kg on lane bits {0,1,3}.
// Reduce-scatter: merge J=2 at stage 1 (cndmask pair + xor1), then xor2
// (quad_perm) + xor8 (row_ror:8) -- all direction-proof (R5).
// R3: bias after reduction | R6: waves_per_eu exact pin | R7: pk half-rate |
// R12: W=16 adds issue without filling the lockstep corridor.

typedef float v2f __attribute__((ext_vector_type(2)));
typedef float v4f __attribute__((ext_vector_type(4)));

#define PKFMA(acc, a, b)                                              \
    asm("v_pk_fma_f32 %0, %1, %2, %0 op_sel:[0,0,0] op_sel_hi:[1,1,1]"\
        : "+v"(acc) : "v"(a), "v"(b))

template<int CTRL>
static __device__ __forceinline__ float dpp_mov(float s) {
    return __int_as_float(__builtin_amdgcn_update_dpp(
        0, __float_as_int(s), CTRL, 0xF, 0xF, true));
}

static __device__ __forceinline__ void pin2(v2f& v) {
    asm volatile("" : "+v"(v));
}

// lgkm-only barrier: LDS writes visible, global loads NOT drained.
static __device__ __forceinline__ void barrier_lgkm() {
    asm volatile("s_waitcnt lgkmcnt(0)" ::: "memory");
    __builtin_amdgcn_s_barrier();
    asm volatile("" ::: "memory");
}

#define LO2(v) __builtin_shufflevector(v, v, 0, 1)
#define HI2(v) __builtin_shufflevector(v, v, 2, 3)

__global__ __launch_bounds__(512)
__attribute__((amdgpu_waves_per_eu(2, 2)))
void rnn_persist_kernel(const float* __restrict__ x,
                        const float* __restrict__ W_ih,
                        const float* __restrict__ W_hh,
                        const float* __restrict__ b_ih,
                        const float* __restrict__ b_hh,
                        const float* __restrict__ W_out,
                        const float* __restrict__ b_out,
                        float* __restrict__ out)
{
    __shared__ __align__(16) float h_lds[2][HBUF];

    const int tid  = threadIdx.x;
    const int b    = blockIdx.x;
    const int w    = tid >> 6;                                   // 0..7
    const int lane = tid & 63;
    const int kg   = (lane & 3) | ((lane >> 1) & 4);             // bits 0,1,3
    const int jgl  = ((lane >> 2) & 1) | (((lane >> 4) & 3) << 1);
    const int jg   = w * 8 + jgl;                                // 0..63
    const int j0   = jg * 2;
    const int b0   = lane & 1;             // which output this lane finalizes
    const bool writer = (lane & 10) == 0;  // bits 1,3 zero: 16 lanes/wave

    const float SC = 2.8853900817779268f;  // 2*log2(e)

    // ---- weights into registers (48 floats, prescaled), pinned ----
    v2f whh2[2][8];   // per jj: 16 floats of W_hh k-slice
    v2f wih2[2][4];   // per jj: 8 floats of W_ih k-slice
    float bs[2];
    #pragma unroll
    for (int jj = 0; jj < 2; ++jj) {
        const v2f* ph = (const v2f*)(W_hh + (j0 + jj) * HH + kg * 16);
        #pragma unroll
        for (int c = 0; c < 8; ++c) whh2[jj][c] = ph[c] * SC;
        const v2f* pi = (const v2f*)(W_ih + (j0 + jj) * XX + kg * 8);
        #pragma unroll
        for (int c = 0; c < 4; ++c) wih2[jj][c] = pi[c] * SC;
        bs[jj] = (b_ih[j0 + jj] + b_hh[j0 + jj]) * SC;
    }
    #pragma unroll
    for (int jj = 0; jj < 2; ++jj) {
        #pragma unroll
        for (int c = 0; c < 8; ++c) pin2(whh2[jj][c]);
        #pragma unroll
        for (int c = 0; c < 4; ++c) pin2(wih2[jj][c]);
    }
    const float bsel = b0 ? bs[1] : bs[0];

    // writer's output index and LDS slot
    const int jw   = j0 + b0;
    const int woff = (jw >> 4) * SSTR + (jw & 15);

    const float* xg = x + (size_t)b * TT * XX + kg * 8;

    if (tid < HBUF) h_lds[0][tid] = 0.f;

    v4f xa0 = ((const v4f*)xg)[0];
    v4f xa1 = ((const v4f*)xg)[1];
    v4f xb0 = ((const v4f*)(xg + XX))[0];
    v4f xb1 = ((const v4f*)(xg + XX))[1];
    __syncthreads();

#define STEP(RP, WP, X0, X1)                                              \
    do {                                                                  \
        const v4f* hp = (const v4f*)&h_lds[RP][kg * SSTR];                \
        const v4f H0 = hp[0], H1 = hp[1], H2 = hp[2], H3 = hp[3];         \
        const v2f h2[8] = { LO2(H0), HI2(H0), LO2(H1), HI2(H1),           \
                            LO2(H2), HI2(H2), LO2(H3), HI2(H3) };         \
        const v2f x2[4] = { LO2(X0), HI2(X0), LO2(X1), HI2(X1) };         \
        float s[2];                                                       \
        _Pragma("unroll")                                                 \
        for (int jj = 0; jj < 2; ++jj) {                                  \
            v2f a = {0.f, 0.f}, c = {0.f, 0.f};                           \
            PKFMA(a, wih2[jj][0], x2[0]); PKFMA(c, wih2[jj][1], x2[1]);   \
            PKFMA(a, wih2[jj][2], x2[2]); PKFMA(c, wih2[jj][3], x2[3]);   \
            PKFMA(a, whh2[jj][0], h2[0]); PKFMA(c, whh2[jj][1], h2[1]);   \
            PKFMA(a, whh2[jj][2], h2[2]); PKFMA(c, whh2[jj][3], h2[3]);   \
            PKFMA(a, whh2[jj][4], h2[4]); PKFMA(c, whh2[jj][5], h2[5]);   \
            PKFMA(a, whh2[jj][6], h2[6]); PKFMA(c, whh2[jj][7], h2[7]);   \
            a = a + c;                                                    \
            s[jj] = a.x + a.y;                                            \
        }                                                                 \
        /* reduce-scatter over kg: merge outputs on bit0, then xor2,xor8 */\
        float u = b0 ? s[1] : s[0];   /* kept output's partial */         \
        float v = b0 ? s[0] : s[1];   /* given to xor1 partner */         \
        u += dpp_mov<0xB1>(v);        /* quad_perm [1,0,3,2] = xor1 */    \
        u += dpp_mov<0x4E>(u);        /* quad_perm [2,3,0,1] = xor2 */    \
        u += dpp_mov<0x128>(u);       /* row_ror:8 = xor8 (dir-proof) */  \
        u += bsel;                    /* bias AFTER reduction (R3) */     \
        const float e  = __builtin_amdgcn_exp2f(u);                       \
        const float hn = fmaf(-2.f, __builtin_amdgcn_rcpf(e + 1.f), 1.f); \
        if (writer) h_lds[WP][woff] = hn;                                 \
        barrier_lgkm();               /* lgkm only: x loads ride across */\
    } while (0)

    for (int t = 0; t < TT; t += 2) {
        STEP(0, 1, xa0, xa1);
        {   // prefetch x for t+2 (2 steps deep; not drained at barriers)
            const int tn = (t + 2 < TT) ? t + 2 : TT - 1;
            const v4f* xp = (const v4f*)(xg + (size_t)tn * XX);
            xa0 = xp[0]; xa1 = xp[1];
        }
        STEP(1, 0, xb0, xb1);
        {   // prefetch x for t+3
            const int tn = (t + 3 < TT) ? t + 3 : TT - 1;
            const v4f* xp = (const v4f*)(xg + (size_t)tn * XX);
            xb0 = xp[0]; xb1 = xp[1];
        }
    }
#undef STEP

    // ---- readout: out[b, :] = h_last @ W_out^T + b_out (h in buffer 0) ----
    if (tid < YY) {
        const float* h  = h_lds[0];
        const float* wr = W_out + tid * HH;
        float r0 = 0.f, r1 = 0.f, r2 = 0.f, r3 = 0.f;
        #pragma unroll
        for (int s8 = 0; s8 < 8; ++s8) {   // 8 slices of 16 floats
            #pragma unroll
            for (int c = 0; c < 4; ++c) {
                const float4 wv = *(const float4*)(wr + s8 * 16 + c * 4);
                const float4 hv = *(const float4*)(h + s8 * SSTR + c * 4);
                r0 = fmaf(wv.x, hv.x, r0); r1 = fmaf(wv.y, hv.y, r1);
                r2 = fmaf(wv.z, hv.z, r2); r3 = fmaf(wv.w, hv.w, r3);
            }
        }
        out[b * YY + tid] = b_out[tid] + ((r0 + r1) + (r2 + r3));
    }
}

extern "C" void kernel_launch(void* const* d_in, const int* in_sizes, int n_in,
                              void* d_out, int out_size, void* d_ws, size_t ws_size,
                              hipStream_t stream) {
    const float* x     = (const float*)d_in[0];
    const float* W_ih  = (const float*)d_in[1];
    const float* W_hh  = (const float*)d_in[2];
    const float* b_ih  = (const float*)d_in[3];
    const float* b_hh  = (const float*)d_in[4];
    const float* W_out = (const float*)d_in[5];
    const float* b_out = (const float*)d_in[6];
    float* out = (float*)d_out;

    rnn_persist_kernel<<<BB, 512, 0, stream>>>(x, W_ih, W_hh, b_ih, b_hh,
                                               W_out, b_out, out);
}